// Round 19
// baseline (56.017 us; speedup 1.0000x reference)
//
#include <hip/hip_runtime.h>

// Log-sparse attention, B=4 H=8 L=4096 E=64 fp32, win_len<=32.
// Round-19: MFMA rewrite. 4 waves/block, 16 queries/wave. Window scores via
// swapped QK^T: S^T[k][q] = mfma_f32_16x16x32_bf16(A=K_band, B=Q^T), so each
// lane's C column IS its query (C layout: col=lane&15, row=4*(lane>>4)+reg,
// HW-verified per guide m89/m91). 3 k-tiles x 2 e-steps = 6 MFMA. Softmax
// across the 4 lanes {q,q+16,q+32,q+48} via shfl_xor(16|32). P exchanged to
// PV B-fragment layout with 12 shfls; V staged TRANSPOSED in LDS so PV
// A-fragments are one ds_read_b128 each (4 e-tiles x 2 k-steps = 8 MFMA).
// Pow2 keys (dist 64..2048) stay VALU: 4 lanes split E, xor-reduce, fused
// into the same softmax; their PV adds f32 into the C accumulators.
// LDS time-shared: K band (96x144B) then V^T (64x208B) = 13.8 KB.

constexpr int L    = 4096;
constexpr int E    = 64;
constexpr int QPB  = 64;           // queries per block (4 waves x 16)
constexpr int WMAX = 32;
constexpr int TPB  = L / QPB;      // 64 tiles per (b,h)
constexpr int NP2  = 6;            // pow2 dists 64..2048
constexpr int KS   = 144;          // K LDS row stride (128 data + 16 pad)
constexpr int VS   = 208;          // Vt LDS row stride (192 data + 16 pad)
constexpr int LDSB = 96 * KS;      // 13824 B >= 64*VS = 13312

typedef short sh8   __attribute__((ext_vector_type(8)));   // 8 bf16 (4 VGPR)
typedef float f32x4 __attribute__((ext_vector_type(4)));

__device__ __forceinline__ unsigned pack2_bf16(float a, float b) {
    unsigned ua = __float_as_uint(a);
    unsigned ub = __float_as_uint(b);
    unsigned ra = (ua + 0x7FFFu + ((ua >> 16) & 1u)) >> 16;  // RNE
    unsigned rb = (ub + 0x7FFFu + ((ub >> 16) & 1u)) >> 16;
    return ra | (rb << 16);
}

__device__ __forceinline__ f32x4 mfma16(sh8 a, sh8 b, f32x4 c) {
    return __builtin_amdgcn_mfma_f32_16x16x32_bf16(a, b, c, 0, 0, 0);
}

struct u4 { unsigned x, y, z, w; };

__global__ __launch_bounds__(256) void logsparse_attn(
    const float* __restrict__ q,
    const float* __restrict__ k,
    const float* __restrict__ v,
    float* __restrict__ out,
    const int* __restrict__ win_ptr)
{
    __shared__ alignas(16) unsigned char buf[LDSB];

    const int bid = blockIdx.x, nb = gridDim.x;
    int swz = bid;
    if ((nb & 7) == 0) {                       // bijective XCD swizzle
        const int cpx = nb >> 3;
        swz = (bid & 7) * cpx + (bid >> 3);
    }
    const int bh  = swz / TPB;
    const int t   = (swz % TPB) * QPB;
    const int tid = threadIdx.x;
    const int w   = tid >> 6;                  // wave 0..3
    const int l   = tid & 63;
    const int g   = l >> 4;                    // lane group 0..3
    const int qq  = l & 15;                    // query-in-tile (also A row idx)
    const int tb  = t + 16 * w;                // wave's query base
    const int i   = tb + qq;                   // this lane's query position
    int win = *win_ptr; win = min(win, WMAX);

    const size_t base = (size_t)bh * (L * E);
    const float* kg = k + base;
    const float* vg = v + base;

    // ---- Q: lane's 16 f32 (e in {8g..8g+7} U {32+8g..32+8g+7}), scaled ----
    float qf[16];
    {
        const float* qp = q + base + (size_t)i * E;
        float4 f0 = *(const float4*)(qp + 8 * g);
        float4 f1 = *(const float4*)(qp + 8 * g + 4);
        float4 f2 = *(const float4*)(qp + 32 + 8 * g);
        float4 f3 = *(const float4*)(qp + 32 + 8 * g + 4);
        qf[0]=f0.x*0.125f; qf[1]=f0.y*0.125f; qf[2]=f0.z*0.125f; qf[3]=f0.w*0.125f;
        qf[4]=f1.x*0.125f; qf[5]=f1.y*0.125f; qf[6]=f1.z*0.125f; qf[7]=f1.w*0.125f;
        qf[8]=f2.x*0.125f; qf[9]=f2.y*0.125f; qf[10]=f2.z*0.125f; qf[11]=f2.w*0.125f;
        qf[12]=f3.x*0.125f; qf[13]=f3.y*0.125f; qf[14]=f3.z*0.125f; qf[15]=f3.w*0.125f;
    }
    // B-fragments for QK^T (e-step 0/1): col=lane&15=q, rows e=8g+32*es+j
    u4 qb[2];
    qb[0] = { pack2_bf16(qf[0], qf[1]),  pack2_bf16(qf[2], qf[3]),
              pack2_bf16(qf[4], qf[5]),  pack2_bf16(qf[6], qf[7]) };
    qb[1] = { pack2_bf16(qf[8], qf[9]),  pack2_bf16(qf[10], qf[11]),
              pack2_bf16(qf[12], qf[13]), pack2_bf16(qf[14], qf[15]) };

    // ---- stage K band rows [t-32, t+64) as bf16, row-major stride 144 ----
    #pragma unroll
    for (int it = 0; it < 6; ++it) {
        int idx = tid + it * 256;
        int r = idx >> 4, wq = idx & 15;
        int j = max(t - WMAX + r, 0);
        float4 fk = *(const float4*)(kg + (size_t)j * E + wq * 4);
        uint2 pk2; pk2.x = pack2_bf16(fk.x, fk.y); pk2.y = pack2_bf16(fk.z, fk.w);
        *(uint2*)(buf + r * KS + wq * 8) = pk2;
    }

    // ---- pow2 scores (global K; overlaps staging). 4 lanes split E,
    //      xor16/32 reduce -> every lane of the query gets the full score.
    float sp2[NP2];
    #pragma unroll
    for (int dd = 0; dd < NP2; ++dd) {
        const int d = 64 << dd;
        sp2[dd] = -60000.f;
        if (t + QPB - 1 >= d) {                // block-uniform skip
            const int j = max(i - d, 0);
            const float* kr = kg + (size_t)j * E;
            float4 h0 = *(const float4*)(kr + 8 * g);
            float4 h1 = *(const float4*)(kr + 8 * g + 4);
            float4 h2 = *(const float4*)(kr + 32 + 8 * g);
            float4 h3 = *(const float4*)(kr + 32 + 8 * g + 4);
            float a = 0.f;
            a = fmaf(h0.x, qf[0],  a); a = fmaf(h0.y, qf[1],  a);
            a = fmaf(h0.z, qf[2],  a); a = fmaf(h0.w, qf[3],  a);
            a = fmaf(h1.x, qf[4],  a); a = fmaf(h1.y, qf[5],  a);
            a = fmaf(h1.z, qf[6],  a); a = fmaf(h1.w, qf[7],  a);
            a = fmaf(h2.x, qf[8],  a); a = fmaf(h2.y, qf[9],  a);
            a = fmaf(h2.z, qf[10], a); a = fmaf(h2.w, qf[11], a);
            a = fmaf(h3.x, qf[12], a); a = fmaf(h3.y, qf[13], a);
            a = fmaf(h3.z, qf[14], a); a = fmaf(h3.w, qf[15], a);
            a += __shfl_xor(a, 16, 64);
            a += __shfl_xor(a, 32, 64);
            if (i >= d) sp2[dd] = a;
        }
    }

    __syncthreads();                           // K staged

    // ---- QK^T: S^T (48k x 16q) = 3 k-tiles x 2 e-steps ----
    f32x4 sc[3];
    #pragma unroll
    for (int tt = 0; tt < 3; ++tt) {
        f32x4 c = {0.f, 0.f, 0.f, 0.f};
        #pragma unroll
        for (int es = 0; es < 2; ++es) {
            int4 araw = *(const int4*)(buf + (16*w + 16*tt + qq) * KS
                                           + (8*g + 32*es) * 2);
            c = mfma16(__builtin_bit_cast(sh8, araw),
                       __builtin_bit_cast(sh8, qb[es]), c);
        }
        sc[tt] = c;
    }

    // ---- mask + softmax (lane holds k = 16t+4g+r for its q = qq) ----
    float p[3][4];
    float lmax = -60000.f;
    #pragma unroll
    for (int tt = 0; tt < 3; ++tt) {
        #pragma unroll
        for (int r = 0; r < 4; ++r) {
            const int kl = 16*tt + 4*g + r;
            const int o  = qq + 32 - kl;       // distance
            const bool isp2  = (o > 0) && ((o & (o - 1)) == 0);
            const bool valid = (o >= 0) && (o <= i) && ((o <= win) || isp2);
            const float sv = valid ? sc[tt][r] : -60000.f;
            p[tt][r] = sv;
            lmax = fmaxf(lmax, sv);
        }
    }
    #pragma unroll
    for (int dd = 0; dd < NP2; ++dd) lmax = fmaxf(lmax, sp2[dd]);
    lmax = fmaxf(lmax, __shfl_xor(lmax, 16, 64));
    lmax = fmaxf(lmax, __shfl_xor(lmax, 32, 64));
    const float m = lmax;

    float lden = 0.f;
    #pragma unroll
    for (int tt = 0; tt < 3; ++tt)
        #pragma unroll
        for (int r = 0; r < 4; ++r) { p[tt][r] = __expf(p[tt][r] - m); lden += p[tt][r]; }
    float pd2[NP2];
    float psum = 0.f;
    #pragma unroll
    for (int dd = 0; dd < NP2; ++dd) { pd2[dd] = __expf(sp2[dd] - m); psum += pd2[dd]; }
    lden += (g == 0) ? psum : 0.f;             // count pow2 once per query
    lden += __shfl_xor(lden, 16, 64);
    lden += __shfl_xor(lden, 32, 64);
    const float inv = 1.f / lden;
    #pragma unroll
    for (int tt = 0; tt < 3; ++tt)
        #pragma unroll
        for (int r = 0; r < 4; ++r) p[tt][r] *= inv;
    #pragma unroll
    for (int dd = 0; dd < NP2; ++dd) pd2[dd] *= inv;

    // ---- P -> PV B-fragments. Target (g, kstep s) needs k=8g+32s+j (j=0..7)
    //      from source groups (2g)&3 and (2g+1)&3 at tile t1=2s+(g>>1).
    unsigned wlo0 = pack2_bf16(p[0][0], p[0][1]);
    unsigned whi0 = pack2_bf16(p[0][2], p[0][3]);
    unsigned wlo1 = pack2_bf16(p[1][0], p[1][1]);
    unsigned whi1 = pack2_bf16(p[1][2], p[1][3]);
    unsigned wlo2 = pack2_bf16(p[2][0], p[2][1]);
    unsigned whi2 = pack2_bf16(p[2][2], p[2][3]);
    const int srcA = qq + 32 * (g & 1);
    const int srcB = srcA + 16;
    // s=0: tiles 0 (g<2) / 1 (g>=2)
    unsigned a00 = __shfl(wlo0, srcA, 64), a01 = __shfl(wlo1, srcA, 64);
    unsigned h00 = __shfl(whi0, srcA, 64), h01 = __shfl(whi1, srcA, 64);
    unsigned b00 = __shfl(wlo0, srcB, 64), b01 = __shfl(wlo1, srcB, 64);
    unsigned k00 = __shfl(whi0, srcB, 64), k01 = __shfl(whi1, srcB, 64);
    const bool hi = (g >= 2);
    u4 Bp0 = { hi ? a01 : a00, hi ? h01 : h00, hi ? b01 : b00, hi ? k01 : k00 };
    // s=1: tile 2 (g<2), zero (g>=2: k 48..63 out of band)
    unsigned a2 = __shfl(wlo2, srcA, 64), h2s = __shfl(whi2, srcA, 64);
    unsigned b2 = __shfl(wlo2, srcB, 64), k2s = __shfl(whi2, srcB, 64);
    u4 Bp1 = { (g < 2) ? a2 : 0u, (g < 2) ? h2s : 0u,
               (g < 2) ? b2 : 0u, (g < 2) ? k2s : 0u };

    __syncthreads();                           // all K reads done

    // ---- stage V^T: Vt[e][k-pair] bf16, stride 208 ----
    #pragma unroll
    for (int it = 0; it < 12; ++it) {
        int idx = tid + it * 256;
        int e = idx & 63, kp = idx >> 6;       // kp 0..47
        int j0 = max(t - WMAX + 2 * kp, 0);
        int j1 = max(t - WMAX + 2 * kp + 1, 0);
        unsigned pw = pack2_bf16(vg[(size_t)j0 * E + e], vg[(size_t)j1 * E + e]);
        *(unsigned*)(buf + e * VS + kp * 4) = pw;
    }
    __syncthreads();                           // V^T staged

    // ---- PV: O^T per e-tile = mfma(A=V^T frag, B=P frag), 4 x 2 ----
    f32x4 oa[4];
    #pragma unroll
    for (int et = 0; et < 4; ++et) { oa[et] = f32x4{0.f, 0.f, 0.f, 0.f}; }
    #pragma unroll
    for (int et = 0; et < 4; ++et) {
        int4 a0 = *(const int4*)(buf + (qq + 16*et) * VS + (16*w + 8*g) * 2);
        oa[et] = mfma16(__builtin_bit_cast(sh8, a0),
                        __builtin_bit_cast(sh8, Bp0), oa[et]);
        int4 a1 = *(const int4*)(buf + (qq + 16*et) * VS + (16*w + 8*g + 32) * 2);
        oa[et] = mfma16(__builtin_bit_cast(sh8, a1),
                        __builtin_bit_cast(sh8, Bp1), oa[et]);
    }

    // ---- pow2 PV: f32 adds into the C accumulators (e' = 16et+4g+r) ----
    #pragma unroll
    for (int dd = 0; dd < NP2; ++dd) {
        const int d = 64 << dd;
        if (t + QPB - 1 >= d) {                // block-uniform skip
            const int j = max(i - d, 0);
            const float* vr = vg + (size_t)j * E;
            const float pdd = pd2[dd];         // 0 if masked
            #pragma unroll
            for (int et = 0; et < 4; ++et) {
                float4 fv = *(const float4*)(vr + 16*et + 4*g);
                oa[et][0] = fmaf(fv.x, pdd, oa[et][0]);
                oa[et][1] = fmaf(fv.y, pdd, oa[et][1]);
                oa[et][2] = fmaf(fv.z, pdd, oa[et][2]);
                oa[et][3] = fmaf(fv.w, pdd, oa[et][3]);
            }
        }
    }

    // ---- write: lane (g,q) owns e' = 16et + 4g + [0..3] of row i ----
    float* op = out + base + (size_t)i * E;
    #pragma unroll
    for (int et = 0; et < 4; ++et) {
        *(f32x4*)(op + 16*et + 4*g) = oa[et];
    }
}

extern "C" void kernel_launch(void* const* d_in, const int* in_sizes, int n_in,
                              void* d_out, int out_size, void* d_ws, size_t ws_size,
                              hipStream_t stream) {
    const float* q = (const float*)d_in[0];
    const float* k = (const float*)d_in[1];
    const float* v = (const float*)d_in[2];
    const int* win = (const int*)d_in[3];
    float* out = (float*)d_out;

    const int n_rows = in_sizes[0] / E;        // B*H*L = 131072
    const int blocks = n_rows / QPB;           // 2048
    logsparse_attn<<<blocks, 256, 0, stream>>>(q, k, v, out, win);
}

// Round 20
// 48.890 us; speedup vs baseline: 1.1458x; 1.1458x over previous
//
#include <hip/hip_runtime.h>

// Log-sparse attention, B=4 H=8 L=4096 E=64 fp32, win_len<=32.
// Quad-per-query, fp16 LDS, fdot2/pk_fma, 4-deep rings (R16/R18 = 43.3us).
// Round-20: amortize block phases over 2x queries WITHOUT touching
// per-thread code: QPB 64->128, 512-thread blocks (8 waves). Same VGPR
// (~52) -> 8 waves/SIMD allowed -> 32 waves/CU (2x R18 measured occupancy);
// halo staging per query -20%; barriers/softmax phases per query halved.
// LDS one time-shared buffer: 160 rows x 160B = 25.6KB (6 blocks fit).
// R19's MFMA path reverted (56us: 1% MfmaUtil, bpermute-heavy P exchange).

constexpr int NT    = 512;           // threads per block
constexpr int L     = 4096;
constexpr int E     = 64;
constexpr int QPB   = 128;           // queries per block (NT/4)
constexpr int WMAX  = 32;
constexpr int WROWS = QPB + WMAX;    // 160 staged rows
constexpr int RS    = 160;           // LDS row stride bytes
constexpr int CS    = 40;            // chunk stride bytes (32 data + 8 pad)
constexpr int TPB   = L / QPB;       // 32 tiles per (b,h)
constexpr int NP2   = 6;             // pow2 dists 64..2048

typedef _Float16 h2  __attribute__((ext_vector_type(2)));   // arithmetic type
typedef __fp16   h2c __attribute__((ext_vector_type(2)));   // builtin interop

__device__ __forceinline__ h2 pkrtz(float a, float b) {
    h2c r = __builtin_amdgcn_cvt_pkrtz(a, b);
    return __builtin_bit_cast(h2, r);
}

#if defined(__has_builtin)
#if __has_builtin(__builtin_amdgcn_fdot2)
#define HAVE_FDOT2 1
#endif
#endif

__device__ __forceinline__ float fdot2h(h2 a, h2 b, float c) {
#ifdef HAVE_FDOT2
    return __builtin_amdgcn_fdot2(__builtin_bit_cast(h2c, a),
                                  __builtin_bit_cast(h2c, b), c, false);
#else
    return fmaf((float)a.x, (float)b.x, fmaf((float)a.y, (float)b.y, c));
#endif
}

__device__ __forceinline__ h2 as_h2(unsigned u) {
    return __builtin_bit_cast(h2, u);
}
__device__ __forceinline__ unsigned as_u32(h2 h) {
    return __builtin_bit_cast(unsigned, h);
}

// ---- DPP quad_perm cross-lane (VALU pipe; 4-lane groups) ----
template<int CTRL>
__device__ __forceinline__ float dppf(float x) {
    return __int_as_float(__builtin_amdgcn_update_dpp(
        0, __float_as_int(x), CTRL, 0xF, 0xF, true));
}
__device__ __forceinline__ float quad_sum(float x) {
    x += dppf<0xB1>(x);   // quad_perm [1,0,3,2]
    x += dppf<0x4E>(x);   // quad_perm [2,3,0,1]
    return x;
}
__device__ __forceinline__ float quad_max(float x) {
    x = fmaxf(x, dppf<0xB1>(x));
    x = fmaxf(x, dppf<0x4E>(x));
    return x;
}
__device__ __forceinline__ float quad_bcast(float x, int r) {
    switch (r & 3) {
    case 0:  return dppf<0x00>(x);
    case 1:  return dppf<0x55>(x);
    case 2:  return dppf<0xAA>(x);
    default: return dppf<0xFF>(x);
    }
}

__global__ __launch_bounds__(NT) void logsparse_attn(
    const float* __restrict__ q,
    const float* __restrict__ k,
    const float* __restrict__ v,
    float* __restrict__ out,
    const int* __restrict__ win_ptr)
{
    __shared__ alignas(16) unsigned char buf[WROWS * RS];   // 25600 B

    const int bid = blockIdx.x, nb = gridDim.x;
    int swz = bid;
    if ((nb & 7) == 0) {                       // bijective XCD swizzle
        const int cpx = nb >> 3;
        swz = (bid & 7) * cpx + (bid >> 3);
    }
    const int bh  = swz / TPB;
    const int t   = (swz % TPB) * QPB;
    const int tid = threadIdx.x;
    const int qid = tid >> 2;                  // query within block (0..127)
    const int s   = tid & 3;                   // lane within quad = chunk id
    const int i   = t + qid;                   // this quad's query position
    const int ce  = s * 16;                    // chunk base element
    int win = *win_ptr; win = min(win, WMAX);

    const size_t base = (size_t)bh * (L * E);
    const float* kb = k + base;
    const float* vb = v + base;

    // ---- this lane's q chunk as 8 x h2, scale folded (1/8) ----
    h2 qh[8];
    {
        const float* qp = q + base + (size_t)i * E + ce;
        #pragma unroll
        for (int u = 0; u < 4; ++u) {
            float4 f = *(const float4*)(qp + u * 4);
            qh[u*2+0] = pkrtz(f.x * 0.125f, f.y * 0.125f);
            qh[u*2+1] = pkrtz(f.z * 0.125f, f.w * 0.125f);
        }
    }

    // ---- stage K window rows [t-32, t+128) as fp16, chunked layout ----
    #pragma unroll
    for (int it = 0; it < (WROWS * 16) / NT; ++it) {   // 5 iters
        int idx = tid + it * NT;
        int r = idx >> 4, w = idx & 15;
        int cc = w >> 2, p = w & 3;
        int j = max(t - WMAX + r, 0);
        float4 fk = *(const float4*)(kb + (size_t)j * E + w * 4);
        uint2 pk; pk.x = as_u32(pkrtz(fk.x, fk.y)); pk.y = as_u32(pkrtz(fk.z, fk.w));
        *(uint2*)(buf + r * RS + cc * CS + p * 8) = pk;
    }

    // ---- pow2 scores BEFORE barrier: global K, overlaps staging stores ----
    float wp[2];
    wp[0] = wp[1] = -60000.f;
    #pragma unroll
    for (int dd = 0; dd < NP2; ++dd) {
        const int d = 64 << dd;
        if (t + QPB - 1 >= d) {                // block-uniform skip
            const int j = max(i - d, 0);
            const float* kr = kb + (size_t)j * E + ce;
            float a0 = 0.f, a1 = 0.f;
            #pragma unroll
            for (int u = 0; u < 4; ++u) {
                float4 f = *(const float4*)(kr + u * 4);
                a0 = fdot2h(pkrtz(f.x, f.y), qh[u*2+0], a0);
                a1 = fdot2h(pkrtz(f.z, f.w), qh[u*2+1], a1);
            }
            float sv = quad_sum(a0 + a1);
            sv = (i >= d) ? sv : -60000.f;
            if (s == ((WMAX + 1 + dd) & 3)) wp[dd < 4 ? 0 : 1] = sv;
        }
    }

    __syncthreads();                           // K staged

    // ---- window scores: 4-deep LDS register ring ----
    float ws[9];
    #pragma unroll
    for (int kk = 0; kk < 9; ++kk) ws[kk] = -60000.f;

    uint2 pf[4][4];
    #pragma unroll
    for (int o = 0; o < 4; ++o) {
        const unsigned char* rp = buf + (qid + WMAX - o) * RS + s * CS;
        pf[o][0] = *(const uint2*)(rp);
        pf[o][1] = *(const uint2*)(rp + 8);
        pf[o][2] = *(const uint2*)(rp + 16);
        pf[o][3] = *(const uint2*)(rp + 24);
    }
    #pragma unroll
    for (int o = 0; o <= WMAX; ++o) {
        float a0 = 0.f, a1 = 0.f;
        a0 = fdot2h(as_h2(pf[o & 3][0].x), qh[0], a0);
        a1 = fdot2h(as_h2(pf[o & 3][0].y), qh[1], a1);
        a0 = fdot2h(as_h2(pf[o & 3][1].x), qh[2], a0);
        a1 = fdot2h(as_h2(pf[o & 3][1].y), qh[3], a1);
        a0 = fdot2h(as_h2(pf[o & 3][2].x), qh[4], a0);
        a1 = fdot2h(as_h2(pf[o & 3][2].y), qh[5], a1);
        a0 = fdot2h(as_h2(pf[o & 3][3].x), qh[6], a0);
        a1 = fdot2h(as_h2(pf[o & 3][3].y), qh[7], a1);
        float sv = quad_sum(a0 + a1);
        const bool isp2  = (o > 0) && ((o & (o - 1)) == 0);
        const bool valid = ((o <= win) || isp2) && (o <= i);
        sv = valid ? sv : -60000.f;
        if (s == (o & 3)) ws[o >> 2] = sv;
        if (o + 4 <= WMAX) {                   // reload this slot with key o+4
            const unsigned char* rp = buf + (qid + WMAX - (o + 4)) * RS + s * CS;
            pf[o & 3][0] = *(const uint2*)(rp);
            pf[o & 3][1] = *(const uint2*)(rp + 8);
            pf[o & 3][2] = *(const uint2*)(rp + 16);
            pf[o & 3][3] = *(const uint2*)(rp + 24);
        }
    }

    // ---- softmax across the quad's distributed scores ----
    float ml = ws[0];
    #pragma unroll
    for (int kk = 1; kk < 9; ++kk) ml = fmaxf(ml, ws[kk]);
    ml = fmaxf(ml, fmaxf(wp[0], wp[1]));
    const float m = quad_max(ml);

    float ew[9], ep0, ep1, dl = 0.f;
    #pragma unroll
    for (int kk = 0; kk < 9; ++kk) { ew[kk] = __expf(ws[kk] - m); dl += ew[kk]; }
    ep0 = __expf(wp[0] - m); ep1 = __expf(wp[1] - m); dl += ep0 + ep1;
    const float inv = 1.0f / quad_sum(dl);
    #pragma unroll
    for (int kk = 0; kk < 9; ++kk) ew[kk] *= inv;
    ep0 *= inv; ep1 *= inv;

    // ---- pow2 PV prefetch (2-deep ring, global; independent of LDS) ----
    float4 vpf[2][4];
    #pragma unroll
    for (int dd = 0; dd < 2; ++dd) {
        if (t + QPB - 1 >= (64 << dd)) {
            const float* vr = vb + (size_t)max(i - (64 << dd), 0) * E + ce;
            vpf[dd][0] = *(const float4*)(vr);
            vpf[dd][1] = *(const float4*)(vr + 4);
            vpf[dd][2] = *(const float4*)(vr + 8);
            vpf[dd][3] = *(const float4*)(vr + 12);
        }
    }

    __syncthreads();                           // all reads of K done

    // ---- restage same buffer with V ----
    #pragma unroll
    for (int it = 0; it < (WROWS * 16) / NT; ++it) {   // 5 iters
        int idx = tid + it * NT;
        int r = idx >> 4, w = idx & 15;
        int cc = w >> 2, p = w & 3;
        int j = max(t - WMAX + r, 0);
        float4 fv = *(const float4*)(vb + (size_t)j * E + w * 4);
        uint2 pv; pv.x = as_u32(pkrtz(fv.x, fv.y)); pv.y = as_u32(pkrtz(fv.z, fv.w));
        *(uint2*)(buf + r * RS + cc * CS + p * 8) = pv;
    }
    __syncthreads();                           // V staged

    // ---- window PV: 4-deep LDS register ring, packed fp16 accumulate ----
    h2 ah[8];
    #pragma unroll
    for (int j = 0; j < 8; ++j) ah[j] = h2{(_Float16)0.f, (_Float16)0.f};

    #pragma unroll
    for (int o = 0; o < 4; ++o) {
        const unsigned char* rp = buf + (qid + WMAX - o) * RS + s * CS;
        pf[o][0] = *(const uint2*)(rp);
        pf[o][1] = *(const uint2*)(rp + 8);
        pf[o][2] = *(const uint2*)(rp + 16);
        pf[o][3] = *(const uint2*)(rp + 24);
    }
    #pragma unroll
    for (int o = 0; o <= WMAX; ++o) {
        const float pd = quad_bcast(ew[o >> 2], o & 3);   // 0 if masked
        const h2 pdh = pkrtz(pd, pd);
        ah[0] += as_h2(pf[o & 3][0].x) * pdh; ah[1] += as_h2(pf[o & 3][0].y) * pdh;
        ah[2] += as_h2(pf[o & 3][1].x) * pdh; ah[3] += as_h2(pf[o & 3][1].y) * pdh;
        ah[4] += as_h2(pf[o & 3][2].x) * pdh; ah[5] += as_h2(pf[o & 3][2].y) * pdh;
        ah[6] += as_h2(pf[o & 3][3].x) * pdh; ah[7] += as_h2(pf[o & 3][3].y) * pdh;
        if (o + 4 <= WMAX) {
            const unsigned char* rp = buf + (qid + WMAX - (o + 4)) * RS + s * CS;
            pf[o & 3][0] = *(const uint2*)(rp);
            pf[o & 3][1] = *(const uint2*)(rp + 8);
            pf[o & 3][2] = *(const uint2*)(rp + 16);
            pf[o & 3][3] = *(const uint2*)(rp + 24);
        }
    }

    // ---- pow2 PV: consume ring, prefetch dd+2 ----
    #pragma unroll
    for (int dd = 0; dd < NP2; ++dd) {
        const int d = 64 << dd;
        if (t + QPB - 1 >= d) {
            const float pd = quad_bcast(dd < 4 ? ep0 : ep1, (WMAX + 1 + dd) & 3);
            const h2 pdh = pkrtz(pd, pd);
            #pragma unroll
            for (int u = 0; u < 4; ++u) {
                float4 f = vpf[dd & 1][u];
                ah[u*2+0] += pkrtz(f.x, f.y) * pdh;
                ah[u*2+1] += pkrtz(f.z, f.w) * pdh;
            }
        }
        if (dd + 2 < NP2 && t + QPB - 1 >= (64 << (dd + 2))) {
            const float* vr = vb + (size_t)max(i - (64 << (dd + 2)), 0) * E + ce;
            vpf[dd & 1][0] = *(const float4*)(vr);
            vpf[dd & 1][1] = *(const float4*)(vr + 4);
            vpf[dd & 1][2] = *(const float4*)(vr + 8);
            vpf[dd & 1][3] = *(const float4*)(vr + 12);
        }
    }

    // ---- write this lane's 64B chunk (quad writes contiguous 256B) ----
    float* op = out + base + (size_t)i * E + ce;
    #pragma unroll
    for (int u = 0; u < 4; ++u) {
        float4 o4;
        o4.x = (float)ah[u*2+0].x; o4.y = (float)ah[u*2+0].y;
        o4.z = (float)ah[u*2+1].x; o4.w = (float)ah[u*2+1].y;
        *(float4*)(op + u * 4) = o4;
    }
}

extern "C" void kernel_launch(void* const* d_in, const int* in_sizes, int n_in,
                              void* d_out, int out_size, void* d_ws, size_t ws_size,
                              hipStream_t stream) {
    const float* q = (const float*)d_in[0];
    const float* k = (const float*)d_in[1];
    const float* v = (const float*)d_in[2];
    const int* win = (const int*)d_in[3];
    float* out = (float*)d_out;

    const int n_rows = in_sizes[0] / E;        // B*H*L = 131072
    const int blocks = n_rows / QPB;           // 1024
    logsparse_attn<<<blocks, NT, 0, stream>>>(q, k, v, out, win);
}

// Round 21
// 43.732 us; speedup vs baseline: 1.2809x; 1.1180x over previous
//
#include <hip/hip_runtime.h>

// Log-sparse attention, B=4 H=8 L=4096 E=64 fp32, win_len<=32.
// Quad-per-query, fp16 LDS, fdot2/pk_fma, 4-deep rings -- R16 structure
// (43.3us session best) reverted verbatim after R17-R20 regressions/nulls.
// Round-21 single change: __launch_bounds__(256, 4) -> allocator budget 128
// VGPR (vs heuristic 48) so the scheduler can hoist the pow2 global rows and
// deepen the LDS rings. Live set ~50-80 floats: no spill possible at cap 128.
// LDS 30.7KB -> 5 blocks/CU = 5 waves/EU >= declared min 4.

constexpr int L     = 4096;
constexpr int E     = 64;
constexpr int QPB   = 64;            // queries per block (256 thr / 4)
constexpr int WMAX  = 32;
constexpr int WROWS = QPB + WMAX;    // 96 staged rows
constexpr int RS    = 160;           // LDS row stride bytes
constexpr int CS    = 40;            // chunk stride bytes (32 data + 8 pad)
constexpr int VOFF  = WROWS * RS;    // V region offset (15360)
constexpr int TPB   = L / QPB;       // 64 tiles per (b,h)
constexpr int NP2   = 6;             // pow2 dists 64..2048

typedef _Float16 h2  __attribute__((ext_vector_type(2)));   // arithmetic type
typedef __fp16   h2c __attribute__((ext_vector_type(2)));   // builtin interop

__device__ __forceinline__ h2 pkrtz(float a, float b) {
    h2c r = __builtin_amdgcn_cvt_pkrtz(a, b);
    return __builtin_bit_cast(h2, r);
}

#if defined(__has_builtin)
#if __has_builtin(__builtin_amdgcn_fdot2)
#define HAVE_FDOT2 1
#endif
#endif

__device__ __forceinline__ float fdot2h(h2 a, h2 b, float c) {
#ifdef HAVE_FDOT2
    return __builtin_amdgcn_fdot2(__builtin_bit_cast(h2c, a),
                                  __builtin_bit_cast(h2c, b), c, false);
#else
    return fmaf((float)a.x, (float)b.x, fmaf((float)a.y, (float)b.y, c));
#endif
}

__device__ __forceinline__ h2 as_h2(unsigned u) {
    return __builtin_bit_cast(h2, u);
}
__device__ __forceinline__ unsigned as_u32(h2 h) {
    return __builtin_bit_cast(unsigned, h);
}

// ---- DPP quad_perm cross-lane (VALU pipe; 4-lane groups) ----
template<int CTRL>
__device__ __forceinline__ float dppf(float x) {
    return __int_as_float(__builtin_amdgcn_update_dpp(
        0, __float_as_int(x), CTRL, 0xF, 0xF, true));
}
__device__ __forceinline__ float quad_sum(float x) {
    x += dppf<0xB1>(x);   // quad_perm [1,0,3,2]
    x += dppf<0x4E>(x);   // quad_perm [2,3,0,1]
    return x;
}
__device__ __forceinline__ float quad_max(float x) {
    x = fmaxf(x, dppf<0xB1>(x));
    x = fmaxf(x, dppf<0x4E>(x));
    return x;
}
__device__ __forceinline__ float quad_bcast(float x, int r) {
    switch (r & 3) {
    case 0:  return dppf<0x00>(x);
    case 1:  return dppf<0x55>(x);
    case 2:  return dppf<0xAA>(x);
    default: return dppf<0xFF>(x);
    }
}

__global__ __launch_bounds__(256, 4) void logsparse_attn(
    const float* __restrict__ q,
    const float* __restrict__ k,
    const float* __restrict__ v,
    float* __restrict__ out,
    const int* __restrict__ win_ptr)
{
    __shared__ alignas(16) unsigned char buf[2 * WROWS * RS];   // 30720 B

    const int bid = blockIdx.x, nb = gridDim.x;
    int swz = bid;
    if ((nb & 7) == 0) {                       // bijective XCD swizzle
        const int cpx = nb >> 3;
        swz = (bid & 7) * cpx + (bid >> 3);
    }
    const int bh  = swz / TPB;
    const int t   = (swz % TPB) * QPB;
    const int tid = threadIdx.x;
    const int qid = tid >> 2;                  // query within block (0..63)
    const int s   = tid & 3;                   // lane within quad = chunk id
    const int i   = t + qid;                   // this quad's query position
    const int ce  = s * 16;                    // chunk base element
    int win = *win_ptr; win = min(win, WMAX);

    const size_t base = (size_t)bh * (L * E);
    const float* kb = k + base;
    const float* vb = v + base;

    // ---- this lane's q chunk as 8 x h2, scale folded (1/8) ----
    h2 qh[8];
    {
        const float* qp = q + base + (size_t)i * E + ce;
        #pragma unroll
        for (int u = 0; u < 4; ++u) {
            float4 f = *(const float4*)(qp + u * 4);
            qh[u*2+0] = pkrtz(f.x * 0.125f, f.y * 0.125f);
            qh[u*2+1] = pkrtz(f.z * 0.125f, f.w * 0.125f);
        }
    }

    // ---- stage K AND V window rows [t-32, t+64) as fp16, chunked layout ----
    #pragma unroll
    for (int it = 0; it < 6; ++it) {
        int idx = tid + it * 256;
        int r = idx >> 4, w = idx & 15;
        int cc = w >> 2, p = w & 3;
        int j = max(t - WMAX + r, 0);
        float4 fk = *(const float4*)(kb + (size_t)j * E + w * 4);
        float4 fv = *(const float4*)(vb + (size_t)j * E + w * 4);
        uint2 pk; pk.x = as_u32(pkrtz(fk.x, fk.y)); pk.y = as_u32(pkrtz(fk.z, fk.w));
        uint2 pv; pv.x = as_u32(pkrtz(fv.x, fv.y)); pv.y = as_u32(pkrtz(fv.z, fv.w));
        *(uint2*)(buf + r * RS + cc * CS + p * 8) = pk;
        *(uint2*)(buf + VOFF + r * RS + cc * CS + p * 8) = pv;
    }

    // ---- pow2 scores BEFORE barrier: global K, overlaps staging stores ----
    float wp[2];
    wp[0] = wp[1] = -60000.f;
    #pragma unroll
    for (int dd = 0; dd < NP2; ++dd) {
        const int d = 64 << dd;
        if (t + QPB - 1 >= d) {                // block-uniform skip
            const int j = max(i - d, 0);
            const float* kr = kb + (size_t)j * E + ce;
            float a0 = 0.f, a1 = 0.f;
            #pragma unroll
            for (int u = 0; u < 4; ++u) {
                float4 f = *(const float4*)(kr + u * 4);
                a0 = fdot2h(pkrtz(f.x, f.y), qh[u*2+0], a0);
                a1 = fdot2h(pkrtz(f.z, f.w), qh[u*2+1], a1);
            }
            float sv = quad_sum(a0 + a1);
            sv = (i >= d) ? sv : -60000.f;
            if (s == ((WMAX + 1 + dd) & 3)) wp[dd < 4 ? 0 : 1] = sv;
        }
    }

    __syncthreads();                 // the ONLY barrier in the kernel

    // ---- window scores: 4-deep LDS register ring ----
    float ws[9];
    #pragma unroll
    for (int kk = 0; kk < 9; ++kk) ws[kk] = -60000.f;

    uint2 pf[4][4];
    #pragma unroll
    for (int o = 0; o < 4; ++o) {
        const unsigned char* rp = buf + (qid + WMAX - o) * RS + s * CS;
        pf[o][0] = *(const uint2*)(rp);
        pf[o][1] = *(const uint2*)(rp + 8);
        pf[o][2] = *(const uint2*)(rp + 16);
        pf[o][3] = *(const uint2*)(rp + 24);
    }
    #pragma unroll
    for (int o = 0; o <= WMAX; ++o) {
        float a0 = 0.f, a1 = 0.f;
        a0 = fdot2h(as_h2(pf[o & 3][0].x), qh[0], a0);
        a1 = fdot2h(as_h2(pf[o & 3][0].y), qh[1], a1);
        a0 = fdot2h(as_h2(pf[o & 3][1].x), qh[2], a0);
        a1 = fdot2h(as_h2(pf[o & 3][1].y), qh[3], a1);
        a0 = fdot2h(as_h2(pf[o & 3][2].x), qh[4], a0);
        a1 = fdot2h(as_h2(pf[o & 3][2].y), qh[5], a1);
        a0 = fdot2h(as_h2(pf[o & 3][3].x), qh[6], a0);
        a1 = fdot2h(as_h2(pf[o & 3][3].y), qh[7], a1);
        float sv = quad_sum(a0 + a1);
        const bool isp2  = (o > 0) && ((o & (o - 1)) == 0);
        const bool valid = ((o <= win) || isp2) && (o <= i);
        sv = valid ? sv : -60000.f;
        if (s == (o & 3)) ws[o >> 2] = sv;
        if (o + 4 <= WMAX) {                   // reload this slot with key o+4
            const unsigned char* rp = buf + (qid + WMAX - (o + 4)) * RS + s * CS;
            pf[o & 3][0] = *(const uint2*)(rp);
            pf[o & 3][1] = *(const uint2*)(rp + 8);
            pf[o & 3][2] = *(const uint2*)(rp + 16);
            pf[o & 3][3] = *(const uint2*)(rp + 24);
        }
    }

    // ---- softmax across the quad's distributed scores ----
    float ml = ws[0];
    #pragma unroll
    for (int kk = 1; kk < 9; ++kk) ml = fmaxf(ml, ws[kk]);
    ml = fmaxf(ml, fmaxf(wp[0], wp[1]));
    const float m = quad_max(ml);

    float ew[9], ep0, ep1, dl = 0.f;
    #pragma unroll
    for (int kk = 0; kk < 9; ++kk) { ew[kk] = __expf(ws[kk] - m); dl += ew[kk]; }
    ep0 = __expf(wp[0] - m); ep1 = __expf(wp[1] - m); dl += ep0 + ep1;
    const float inv = 1.0f / quad_sum(dl);
    #pragma unroll
    for (int kk = 0; kk < 9; ++kk) ew[kk] *= inv;
    ep0 *= inv; ep1 *= inv;

    // ---- pow2 PV prefetch (2-deep ring), issued before window PV ----
    float4 vpf[2][4];
    #pragma unroll
    for (int dd = 0; dd < 2; ++dd) {
        if (t + QPB - 1 >= (64 << dd)) {
            const float* vr = vb + (size_t)max(i - (64 << dd), 0) * E + ce;
            vpf[dd][0] = *(const float4*)(vr);
            vpf[dd][1] = *(const float4*)(vr + 4);
            vpf[dd][2] = *(const float4*)(vr + 8);
            vpf[dd][3] = *(const float4*)(vr + 12);
        }
    }

    // ---- window PV: 4-deep LDS register ring, packed fp16 accumulate ----
    h2 ah[8];
    #pragma unroll
    for (int j = 0; j < 8; ++j) ah[j] = h2{(_Float16)0.f, (_Float16)0.f};

    #pragma unroll
    for (int o = 0; o < 4; ++o) {
        const unsigned char* rp = buf + VOFF + (qid + WMAX - o) * RS + s * CS;
        pf[o][0] = *(const uint2*)(rp);
        pf[o][1] = *(const uint2*)(rp + 8);
        pf[o][2] = *(const uint2*)(rp + 16);
        pf[o][3] = *(const uint2*)(rp + 24);
    }
    #pragma unroll
    for (int o = 0; o <= WMAX; ++o) {
        const float pd = quad_bcast(ew[o >> 2], o & 3);   // 0 if masked
        const h2 pdh = pkrtz(pd, pd);
        ah[0] += as_h2(pf[o & 3][0].x) * pdh; ah[1] += as_h2(pf[o & 3][0].y) * pdh;
        ah[2] += as_h2(pf[o & 3][1].x) * pdh; ah[3] += as_h2(pf[o & 3][1].y) * pdh;
        ah[4] += as_h2(pf[o & 3][2].x) * pdh; ah[5] += as_h2(pf[o & 3][2].y) * pdh;
        ah[6] += as_h2(pf[o & 3][3].x) * pdh; ah[7] += as_h2(pf[o & 3][3].y) * pdh;
        if (o + 4 <= WMAX) {
            const unsigned char* rp = buf + VOFF + (qid + WMAX - (o + 4)) * RS + s * CS;
            pf[o & 3][0] = *(const uint2*)(rp);
            pf[o & 3][1] = *(const uint2*)(rp + 8);
            pf[o & 3][2] = *(const uint2*)(rp + 16);
            pf[o & 3][3] = *(const uint2*)(rp + 24);
        }
    }

    // ---- pow2 PV: consume ring, prefetch dd+2 ----
    #pragma unroll
    for (int dd = 0; dd < NP2; ++dd) {
        const int d = 64 << dd;
        if (t + QPB - 1 >= d) {
            const float pd = quad_bcast(dd < 4 ? ep0 : ep1, (WMAX + 1 + dd) & 3);
            const h2 pdh = pkrtz(pd, pd);
            #pragma unroll
            for (int u = 0; u < 4; ++u) {
                float4 f = vpf[dd & 1][u];
                ah[u*2+0] += pkrtz(f.x, f.y) * pdh;
                ah[u*2+1] += pkrtz(f.z, f.w) * pdh;
            }
        }
        if (dd + 2 < NP2 && t + QPB - 1 >= (64 << (dd + 2))) {
            const float* vr = vb + (size_t)max(i - (64 << (dd + 2)), 0) * E + ce;
            vpf[dd & 1][0] = *(const float4*)(vr);
            vpf[dd & 1][1] = *(const float4*)(vr + 4);
            vpf[dd & 1][2] = *(const float4*)(vr + 8);
            vpf[dd & 1][3] = *(const float4*)(vr + 12);
        }
    }

    // ---- write this lane's 64B chunk (quad writes contiguous 256B) ----
    float* op = out + base + (size_t)i * E + ce;
    #pragma unroll
    for (int u = 0; u < 4; ++u) {
        float4 o4;
        o4.x = (float)ah[u*2+0].x; o4.y = (float)ah[u*2+0].y;
        o4.z = (float)ah[u*2+1].x; o4.w = (float)ah[u*2+1].y;
        *(float4*)(op + u * 4) = o4;
    }
}

extern "C" void kernel_launch(void* const* d_in, const int* in_sizes, int n_in,
                              void* d_out, int out_size, void* d_ws, size_t ws_size,
                              hipStream_t stream) {
    const float* q = (const float*)d_in[0];
    const float* k = (const float*)d_in[1];
    const float* v = (const float*)d_in[2];
    const int* win = (const int*)d_in[3];
    float* out = (float*)d_out;

    const int n_rows = in_sizes[0] / E;        // B*H*L = 131072
    const int blocks = n_rows / QPB;           // 2048
    logsparse_attn<<<blocks, 256, 0, stream>>>(q, k, v, out, win);
}

// Round 22
// 43.697 us; speedup vs baseline: 1.2819x; 1.0008x over previous
//
#include <hip/hip_runtime.h>

// Log-sparse attention, B=4 H=8 L=4096 E=64 fp32, win_len<=32.
// Quad-per-query, fp16 LDS, fdot2/pk_fma, R16 structure (43.3us best).
// Round-22: ENFORCE the 4-deep ring with asm volatile memory fences.
// Evidence: R16/R21 compiled to VGPR=48 < the 51+ the declared ring needs
// -> the compiler sank each ring reload to its use (pipeline depth ~1).
// A ""::: "memory" fence at each ring-iteration end is a compile-time-only
// ordering barrier (no waitcnt, no VALU pinning): reloads must issue in
// their own iteration, 4 ahead of consumption -> ring materializes.

constexpr int L     = 4096;
constexpr int E     = 64;
constexpr int QPB   = 64;            // queries per block (256 thr / 4)
constexpr int WMAX  = 32;
constexpr int WROWS = QPB + WMAX;    // 96 staged rows
constexpr int RS    = 160;           // LDS row stride bytes
constexpr int CS    = 40;            // chunk stride bytes (32 data + 8 pad)
constexpr int VOFF  = WROWS * RS;    // V region offset (15360)
constexpr int TPB   = L / QPB;       // 64 tiles per (b,h)
constexpr int NP2   = 6;             // pow2 dists 64..2048

#define MEMFENCE() asm volatile("" ::: "memory")

typedef _Float16 h2  __attribute__((ext_vector_type(2)));   // arithmetic type
typedef __fp16   h2c __attribute__((ext_vector_type(2)));   // builtin interop

__device__ __forceinline__ h2 pkrtz(float a, float b) {
    h2c r = __builtin_amdgcn_cvt_pkrtz(a, b);
    return __builtin_bit_cast(h2, r);
}

#if defined(__has_builtin)
#if __has_builtin(__builtin_amdgcn_fdot2)
#define HAVE_FDOT2 1
#endif
#endif

__device__ __forceinline__ float fdot2h(h2 a, h2 b, float c) {
#ifdef HAVE_FDOT2
    return __builtin_amdgcn_fdot2(__builtin_bit_cast(h2c, a),
                                  __builtin_bit_cast(h2c, b), c, false);
#else
    return fmaf((float)a.x, (float)b.x, fmaf((float)a.y, (float)b.y, c));
#endif
}

__device__ __forceinline__ h2 as_h2(unsigned u) {
    return __builtin_bit_cast(h2, u);
}
__device__ __forceinline__ unsigned as_u32(h2 h) {
    return __builtin_bit_cast(unsigned, h);
}

// ---- DPP quad_perm cross-lane (VALU pipe; 4-lane groups) ----
template<int CTRL>
__device__ __forceinline__ float dppf(float x) {
    return __int_as_float(__builtin_amdgcn_update_dpp(
        0, __float_as_int(x), CTRL, 0xF, 0xF, true));
}
__device__ __forceinline__ float quad_sum(float x) {
    x += dppf<0xB1>(x);   // quad_perm [1,0,3,2]
    x += dppf<0x4E>(x);   // quad_perm [2,3,0,1]
    return x;
}
__device__ __forceinline__ float quad_max(float x) {
    x = fmaxf(x, dppf<0xB1>(x));
    x = fmaxf(x, dppf<0x4E>(x));
    return x;
}
__device__ __forceinline__ float quad_bcast(float x, int r) {
    switch (r & 3) {
    case 0:  return dppf<0x00>(x);
    case 1:  return dppf<0x55>(x);
    case 2:  return dppf<0xAA>(x);
    default: return dppf<0xFF>(x);
    }
}

__global__ __launch_bounds__(256) void logsparse_attn(
    const float* __restrict__ q,
    const float* __restrict__ k,
    const float* __restrict__ v,
    float* __restrict__ out,
    const int* __restrict__ win_ptr)
{
    __shared__ alignas(16) unsigned char buf[2 * WROWS * RS];   // 30720 B

    const int bid = blockIdx.x, nb = gridDim.x;
    int swz = bid;
    if ((nb & 7) == 0) {                       // bijective XCD swizzle
        const int cpx = nb >> 3;
        swz = (bid & 7) * cpx + (bid >> 3);
    }
    const int bh  = swz / TPB;
    const int t   = (swz % TPB) * QPB;
    const int tid = threadIdx.x;
    const int qid = tid >> 2;                  // query within block (0..63)
    const int s   = tid & 3;                   // lane within quad = chunk id
    const int i   = t + qid;                   // this quad's query position
    const int ce  = s * 16;                    // chunk base element
    int win = *win_ptr; win = min(win, WMAX);

    const size_t base = (size_t)bh * (L * E);
    const float* kb = k + base;
    const float* vb = v + base;

    // ---- this lane's q chunk as 8 x h2, scale folded (1/8) ----
    h2 qh[8];
    {
        const float* qp = q + base + (size_t)i * E + ce;
        #pragma unroll
        for (int u = 0; u < 4; ++u) {
            float4 f = *(const float4*)(qp + u * 4);
            qh[u*2+0] = pkrtz(f.x * 0.125f, f.y * 0.125f);
            qh[u*2+1] = pkrtz(f.z * 0.125f, f.w * 0.125f);
        }
    }

    // ---- stage K AND V window rows [t-32, t+64) as fp16, chunked layout ----
    #pragma unroll
    for (int it = 0; it < 6; ++it) {
        int idx = tid + it * 256;
        int r = idx >> 4, w = idx & 15;
        int cc = w >> 2, p = w & 3;
        int j = max(t - WMAX + r, 0);
        float4 fk = *(const float4*)(kb + (size_t)j * E + w * 4);
        float4 fv = *(const float4*)(vb + (size_t)j * E + w * 4);
        uint2 pk; pk.x = as_u32(pkrtz(fk.x, fk.y)); pk.y = as_u32(pkrtz(fk.z, fk.w));
        uint2 pv; pv.x = as_u32(pkrtz(fv.x, fv.y)); pv.y = as_u32(pkrtz(fv.z, fv.w));
        *(uint2*)(buf + r * RS + cc * CS + p * 8) = pk;
        *(uint2*)(buf + VOFF + r * RS + cc * CS + p * 8) = pv;
    }

    // ---- pow2 scores BEFORE barrier: global K, overlaps staging stores ----
    float wp[2];
    wp[0] = wp[1] = -60000.f;
    #pragma unroll
    for (int dd = 0; dd < NP2; ++dd) {
        const int d = 64 << dd;
        if (t + QPB - 1 >= d) {                // block-uniform skip
            const int j = max(i - d, 0);
            const float* kr = kb + (size_t)j * E + ce;
            float a0 = 0.f, a1 = 0.f;
            #pragma unroll
            for (int u = 0; u < 4; ++u) {
                float4 f = *(const float4*)(kr + u * 4);
                a0 = fdot2h(pkrtz(f.x, f.y), qh[u*2+0], a0);
                a1 = fdot2h(pkrtz(f.z, f.w), qh[u*2+1], a1);
            }
            float sv = quad_sum(a0 + a1);
            sv = (i >= d) ? sv : -60000.f;
            if (s == ((WMAX + 1 + dd) & 3)) wp[dd < 4 ? 0 : 1] = sv;
        }
    }

    __syncthreads();                 // the ONLY barrier in the kernel

    // ---- window scores: 4-deep LDS register ring (fence-enforced) ----
    float ws[9];
    #pragma unroll
    for (int kk = 0; kk < 9; ++kk) ws[kk] = -60000.f;

    uint2 pf[4][4];
    #pragma unroll
    for (int o = 0; o < 4; ++o) {
        const unsigned char* rp = buf + (qid + WMAX - o) * RS + s * CS;
        pf[o][0] = *(const uint2*)(rp);
        pf[o][1] = *(const uint2*)(rp + 8);
        pf[o][2] = *(const uint2*)(rp + 16);
        pf[o][3] = *(const uint2*)(rp + 24);
    }
    MEMFENCE();                                // prefetch issued before loop
    #pragma unroll
    for (int o = 0; o <= WMAX; ++o) {
        float a0 = 0.f, a1 = 0.f;
        a0 = fdot2h(as_h2(pf[o & 3][0].x), qh[0], a0);
        a1 = fdot2h(as_h2(pf[o & 3][0].y), qh[1], a1);
        a0 = fdot2h(as_h2(pf[o & 3][1].x), qh[2], a0);
        a1 = fdot2h(as_h2(pf[o & 3][1].y), qh[3], a1);
        a0 = fdot2h(as_h2(pf[o & 3][2].x), qh[4], a0);
        a1 = fdot2h(as_h2(pf[o & 3][2].y), qh[5], a1);
        a0 = fdot2h(as_h2(pf[o & 3][3].x), qh[6], a0);
        a1 = fdot2h(as_h2(pf[o & 3][3].y), qh[7], a1);
        float sv = quad_sum(a0 + a1);
        const bool isp2  = (o > 0) && ((o & (o - 1)) == 0);
        const bool valid = ((o <= win) || isp2) && (o <= i);
        sv = valid ? sv : -60000.f;
        if (s == (o & 3)) ws[o >> 2] = sv;
        if (o + 4 <= WMAX) {                   // reload this slot with key o+4
            const unsigned char* rp = buf + (qid + WMAX - (o + 4)) * RS + s * CS;
            pf[o & 3][0] = *(const uint2*)(rp);
            pf[o & 3][1] = *(const uint2*)(rp + 8);
            pf[o & 3][2] = *(const uint2*)(rp + 16);
            pf[o & 3][3] = *(const uint2*)(rp + 24);
        }
        MEMFENCE();                            // reload can't sink past here
    }

    // ---- softmax across the quad's distributed scores ----
    float ml = ws[0];
    #pragma unroll
    for (int kk = 1; kk < 9; ++kk) ml = fmaxf(ml, ws[kk]);
    ml = fmaxf(ml, fmaxf(wp[0], wp[1]));
    const float m = quad_max(ml);

    float ew[9], ep0, ep1, dl = 0.f;
    #pragma unroll
    for (int kk = 0; kk < 9; ++kk) { ew[kk] = __expf(ws[kk] - m); dl += ew[kk]; }
    ep0 = __expf(wp[0] - m); ep1 = __expf(wp[1] - m); dl += ep0 + ep1;
    const float inv = 1.0f / quad_sum(dl);
    #pragma unroll
    for (int kk = 0; kk < 9; ++kk) ew[kk] *= inv;
    ep0 *= inv; ep1 *= inv;

    // ---- pow2 PV prefetch (2-deep ring), issued before window PV ----
    float4 vpf[2][4];
    #pragma unroll
    for (int dd = 0; dd < 2; ++dd) {
        if (t + QPB - 1 >= (64 << dd)) {
            const float* vr = vb + (size_t)max(i - (64 << dd), 0) * E + ce;
            vpf[dd][0] = *(const float4*)(vr);
            vpf[dd][1] = *(const float4*)(vr + 4);
            vpf[dd][2] = *(const float4*)(vr + 8);
            vpf[dd][3] = *(const float4*)(vr + 12);
        }
    }
    MEMFENCE();                                // vpf loads issue here

    // ---- window PV: 4-deep LDS register ring (fence-enforced) ----
    h2 ah[8];
    #pragma unroll
    for (int j = 0; j < 8; ++j) ah[j] = h2{(_Float16)0.f, (_Float16)0.f};

    #pragma unroll
    for (int o = 0; o < 4; ++o) {
        const unsigned char* rp = buf + VOFF + (qid + WMAX - o) * RS + s * CS;
        pf[o][0] = *(const uint2*)(rp);
        pf[o][1] = *(const uint2*)(rp + 8);
        pf[o][2] = *(const uint2*)(rp + 16);
        pf[o][3] = *(const uint2*)(rp + 24);
    }
    MEMFENCE();
    #pragma unroll
    for (int o = 0; o <= WMAX; ++o) {
        const float pd = quad_bcast(ew[o >> 2], o & 3);   // 0 if masked
        const h2 pdh = pkrtz(pd, pd);
        ah[0] += as_h2(pf[o & 3][0].x) * pdh; ah[1] += as_h2(pf[o & 3][0].y) * pdh;
        ah[2] += as_h2(pf[o & 3][1].x) * pdh; ah[3] += as_h2(pf[o & 3][1].y) * pdh;
        ah[4] += as_h2(pf[o & 3][2].x) * pdh; ah[5] += as_h2(pf[o & 3][2].y) * pdh;
        ah[6] += as_h2(pf[o & 3][3].x) * pdh; ah[7] += as_h2(pf[o & 3][3].y) * pdh;
        if (o + 4 <= WMAX) {
            const unsigned char* rp = buf + VOFF + (qid + WMAX - (o + 4)) * RS + s * CS;
            pf[o & 3][0] = *(const uint2*)(rp);
            pf[o & 3][1] = *(const uint2*)(rp + 8);
            pf[o & 3][2] = *(const uint2*)(rp + 16);
            pf[o & 3][3] = *(const uint2*)(rp + 24);
        }
        MEMFENCE();
    }

    // ---- pow2 PV: consume ring, prefetch dd+2 (fence-enforced) ----
    #pragma unroll
    for (int dd = 0; dd < NP2; ++dd) {
        const int d = 64 << dd;
        if (t + QPB - 1 >= d) {
            const float pd = quad_bcast(dd < 4 ? ep0 : ep1, (WMAX + 1 + dd) & 3);
            const h2 pdh = pkrtz(pd, pd);
            #pragma unroll
            for (int u = 0; u < 4; ++u) {
                float4 f = vpf[dd & 1][u];
                ah[u*2+0] += pkrtz(f.x, f.y) * pdh;
                ah[u*2+1] += pkrtz(f.z, f.w) * pdh;
            }
        }
        if (dd + 2 < NP2 && t + QPB - 1 >= (64 << (dd + 2))) {
            const float* vr = vb + (size_t)max(i - (64 << (dd + 2)), 0) * E + ce;
            vpf[dd & 1][0] = *(const float4*)(vr);
            vpf[dd & 1][1] = *(const float4*)(vr + 4);
            vpf[dd & 1][2] = *(const float4*)(vr + 8);
            vpf[dd & 1][3] = *(const float4*)(vr + 12);
        }
        MEMFENCE();
    }

    // ---- write this lane's 64B chunk (quad writes contiguous 256B) ----
    float* op = out + base + (size_t)i * E + ce;
    #pragma unroll
    for (int u = 0; u < 4; ++u) {
        float4 o4;
        o4.x = (float)ah[u*2+0].x; o4.y = (float)ah[u*2+0].y;
        o4.z = (float)ah[u*2+1].x; o4.w = (float)ah[u*2+1].y;
        *(float4*)(op + u * 4) = o4;
    }
}

extern "C" void kernel_launch(void* const* d_in, const int* in_sizes, int n_in,
                              void* d_out, int out_size, void* d_ws, size_t ws_size,
                              hipStream_t stream) {
    const float* q = (const float*)d_in[0];
    const float* k = (const float*)d_in[1];
    const float* v = (const float*)d_in[2];
    const int* win = (const int*)d_in[3];
    float* out = (float*)d_out;

    const int n_rows = in_sizes[0] / E;        // B*H*L = 131072
    const int blocks = n_rows / QPB;           // 2048
    logsparse_attn<<<blocks, 256, 0, stream>>>(q, k, v, out, win);
}